// Round 6
// baseline (963.381 us; speedup 1.0000x reference)
//
#include <hip/hip_runtime.h>

#define N_NODES 100000
#define N_EDGES 1600000
#define IN_CH 8
#define HID_CH 64
#define OUT_CH 2

#define E2 (N_EDGES / 2)   // int2-vectorized edge count (1.6M even)

// ---- workspace (4-byte words), 4.8 MB ----
//   sum  : N*8 floats @ 0        (memset 0; layer-1 neighbor feature sums)
//   cnt  : N   ints   @ N*8      (memset 0; in-degree)
//   g    : N*2 floats @ N*9      (W_l2 @ h per node; written before read)
//   invb : N   floats @ N*11     (1/max(deg,1);    written before read)
#define WS_SUM 0
#define WS_CNT (N_NODES * 8)
#define WS_G   (N_NODES * 9)
#define WS_INV (N_NODES * 11)

// Native fire-and-forget float atomic (global_atomic_add_f32 on gfx950).
__device__ __forceinline__ void gfadd(float* p, float v) {
    unsafeAtomicAdd(p, v);
}

// Layer-1 scatter, edge-parallel, NO binning: per edge gather x[src] (32B,
// L2-hot: x is 3.2MB) and scatter-add into sum[dst] (8 f32 atomics) + cnt
// (1 int atomic). All iterations independent -> fully pipelined; atomics
// execute memory-side (no return, no latency chain in the thread).
__global__ __launch_bounds__(256) void l1_scatter(
        const int* __restrict__ src, const int* __restrict__ dst,
        const float* __restrict__ x,
        float* __restrict__ sum, int* __restrict__ cnt) {
    const int2* s2 = (const int2*)src;
    const int2* d2 = (const int2*)dst;
    int stride = gridDim.x * blockDim.x;
    for (int i = blockIdx.x * blockDim.x + threadIdx.x; i < E2; i += stride) {
        int2 s = s2[i];
        int2 d = d2[i];
        {
            const float4* xs = (const float4*)(x + (size_t)s.x * IN_CH);
            float4 a = xs[0];
            float4 b = xs[1];
            float* p = sum + (size_t)d.x * IN_CH;
            gfadd(p + 0, a.x); gfadd(p + 1, a.y);
            gfadd(p + 2, a.z); gfadd(p + 3, a.w);
            gfadd(p + 4, b.x); gfadd(p + 5, b.y);
            gfadd(p + 6, b.z); gfadd(p + 7, b.w);
            atomicAdd(cnt + d.x, 1);
        }
        {
            const float4* xs = (const float4*)(x + (size_t)s.y * IN_CH);
            float4 a = xs[0];
            float4 b = xs[1];
            float* p = sum + (size_t)d.y * IN_CH;
            gfadd(p + 0, a.x); gfadd(p + 1, a.y);
            gfadd(p + 2, a.z); gfadd(p + 3, a.w);
            gfadd(p + 4, b.x); gfadd(p + 5, b.y);
            gfadd(p + 6, b.z); gfadd(p + 7, b.w);
            atomicAdd(cnt + d.y, 1);
        }
    }
}

// Node-parallel MLP (proven 4-lane distributed scheme): ag = sum*inv,
// h = relu(W_l1 ag + b1 + W_r1 x), g = W_l2 h, rt = W_r2 h + b2.
// Writes g, invb, and out = rt (full overwrite -> replay-safe; layer-2
// scatter then atomically accumulates on top).
__global__ __launch_bounds__(512) void mlp_node(
        const float* __restrict__ x,
        const float* __restrict__ sum, const int* __restrict__ cnt,
        const float* __restrict__ W_l1, const float* __restrict__ b_l1,
        const float* __restrict__ W_r1,
        const float* __restrict__ W_l2, const float* __restrict__ b_l2,
        const float* __restrict__ W_r2,
        float* __restrict__ g, float* __restrict__ invb,
        float* __restrict__ out) {
    __shared__ float sWl[HID_CH * IN_CH];
    __shared__ float sWr[HID_CH * IN_CH];
    __shared__ float sb[HID_CH];
    __shared__ float sWl2[OUT_CH * HID_CH];
    __shared__ float sWr2[OUT_CH * HID_CH];
    __shared__ float sb2[OUT_CH];

    int tid = threadIdx.x;
    for (int i = tid; i < HID_CH * IN_CH; i += 512) {
        sWl[i] = W_l1[i];
        sWr[i] = W_r1[i];
    }
    for (int i = tid; i < HID_CH; i += 512) sb[i] = b_l1[i];
    for (int i = tid; i < OUT_CH * HID_CH; i += 512) {
        sWl2[i] = W_l2[i];
        sWr2[i] = W_r2[i];
    }
    if (tid < OUT_CH) sb2[tid] = b_l2[tid];
    __syncthreads();

    // 4 lanes per node, 128 nodes per block.
    int q = tid >> 2;
    int l = tid & 3;
    int node = blockIdx.x * 128 + q;
    if (node >= N_NODES) return;

    int dn = cnt[node];
    float inv = 1.0f / fmaxf((float)dn, 1.0f);

    float ag[IN_CH], xa[IN_CH];
    const float4* sp = (const float4*)(sum + (size_t)node * IN_CH);
    float4 s0 = sp[0], s1 = sp[1];
    ag[0] = s0.x * inv; ag[1] = s0.y * inv; ag[2] = s0.z * inv; ag[3] = s0.w * inv;
    ag[4] = s1.x * inv; ag[5] = s1.y * inv; ag[6] = s1.z * inv; ag[7] = s1.w * inv;
    const float4* xp = (const float4*)(x + (size_t)node * IN_CH);
    float4 x0 = xp[0], x1 = xp[1];
    xa[0] = x0.x; xa[1] = x0.y; xa[2] = x0.z; xa[3] = x0.w;
    xa[4] = x1.x; xa[5] = x1.y; xa[6] = x1.z; xa[7] = x1.w;

    // Distributed MLP: lane l handles hidden units [16l, 16l+16).
    float g0 = 0.f, g1 = 0.f, r0 = 0.f, r1 = 0.f;
    int k0 = l * 16;
    #pragma unroll 4
    for (int kk = k0; kk < k0 + 16; kk++) {
        float hk = sb[kk];
        #pragma unroll
        for (int c = 0; c < IN_CH; c++) {
            hk += sWl[kk * IN_CH + c] * ag[c];
            hk += sWr[kk * IN_CH + c] * xa[c];
        }
        hk = fmaxf(hk, 0.0f);   // ReLU (dropout identity in eval)
        g0 += sWl2[kk] * hk;
        g1 += sWl2[HID_CH + kk] * hk;
        r0 += sWr2[kk] * hk;
        r1 += sWr2[HID_CH + kk] * hk;
    }
    g0 += __shfl_xor(g0, 1); g0 += __shfl_xor(g0, 2);
    g1 += __shfl_xor(g1, 1); g1 += __shfl_xor(g1, 2);
    r0 += __shfl_xor(r0, 1); r0 += __shfl_xor(r0, 2);
    r1 += __shfl_xor(r1, 1); r1 += __shfl_xor(r1, 2);
    if (l == 0) {
        float2 gv;
        gv.x = g0;
        gv.y = g1;
        *(float2*)(g + (size_t)node * 2) = gv;
        invb[node] = inv;
        float2 rt;
        rt.x = r0 + sb2[0];
        rt.y = r1 + sb2[1];
        *(float2*)(out + (size_t)node * 2) = rt;   // overwrite: replay-safe
    }
}

// Layer-2 scatter, edge-parallel: gather g[src] (8B, L2-hot 800KB) and
// invb[dst] (4B), scatter-add g*inv into out[dst] (2 f32 atomics).
// out = rt + sum_{src} g[src]/deg  == reference layer 2.
__global__ __launch_bounds__(256) void l2_scatter(
        const int* __restrict__ src, const int* __restrict__ dst,
        const float* __restrict__ g, const float* __restrict__ invb,
        float* __restrict__ out) {
    const int2* s2 = (const int2*)src;
    const int2* d2 = (const int2*)dst;
    int stride = gridDim.x * blockDim.x;
    for (int i = blockIdx.x * blockDim.x + threadIdx.x; i < E2; i += stride) {
        int2 s = s2[i];
        int2 d = d2[i];
        {
            float2 gv = *(const float2*)(g + (size_t)s.x * 2);
            float iv = invb[d.x];
            float* p = out + (size_t)d.x * 2;
            gfadd(p + 0, gv.x * iv);
            gfadd(p + 1, gv.y * iv);
        }
        {
            float2 gv = *(const float2*)(g + (size_t)s.y * 2);
            float iv = invb[d.y];
            float* p = out + (size_t)d.y * 2;
            gfadd(p + 0, gv.x * iv);
            gfadd(p + 1, gv.y * iv);
        }
    }
}

extern "C" void kernel_launch(void* const* d_in, const int* in_sizes, int n_in,
                              void* d_out, int out_size, void* d_ws, size_t ws_size,
                              hipStream_t stream) {
    const float* x    = (const float*)d_in[0];
    const int*   ei   = (const int*)d_in[1];   // [2, N_EDGES] int32 per harness
    const float* W_l1 = (const float*)d_in[2];
    const float* b_l1 = (const float*)d_in[3];
    const float* W_r1 = (const float*)d_in[4];
    const float* W_l2 = (const float*)d_in[5];
    const float* b_l2 = (const float*)d_in[6];
    const float* W_r2 = (const float*)d_in[7];
    float* out = (float*)d_out;

    const int* src = ei;
    const int* dst = ei + N_EDGES;

    float* sum  = (float*)d_ws + WS_SUM;
    int*   cnt  = (int*)d_ws + WS_CNT;
    float* g    = (float*)d_ws + WS_G;
    float* invb = (float*)d_ws + WS_INV;

    // Zero sum+cnt (contiguous 9N words = 3.6MB).
    hipMemsetAsync(d_ws, 0, (size_t)N_NODES * 9 * sizeof(int), stream);

    l1_scatter<<<2048, 256, 0, stream>>>(src, dst, x, sum, cnt);
    mlp_node<<<(N_NODES + 127) / 128, 512, 0, stream>>>(
        x, sum, cnt, W_l1, b_l1, W_r1, W_l2, b_l2, W_r2, g, invb, out);
    l2_scatter<<<2048, 256, 0, stream>>>(src, dst, g, invb, out);
}

// Round 7
// 135.833 us; speedup vs baseline: 7.0924x; 7.0924x over previous
//
#include <hip/hip_runtime.h>

#define N_NODES 100000
#define N_EDGES 1600000
#define IN_CH 8
#define HID_CH 64
#define OUT_CH 2

// 1024 dst-ranges of 98 nodes (1024*98 = 100352 >= 100000).
#define R2   1024
#define RN   98
#define CAP  1920    // per-range capacity; Binom mean 1568, sd ~40 -> +8.9 sigma
#define CSTRIDE 16   // cursor padded to one range per 64B line

// Ownership-filtered binning: 256 blocks = 32 chunks x 8 owners.
// Block (chunk, own) scans its 50K-edge chunk, keeps only ranges with
// r&7==own. Per-(block,range) bucket spans ~49 ints (3 full lines),
// single-writer -> no cross-XCD partial-line amplification (round-6 lesson:
// scattered multi-XCD partial-line writes amplify ~125x to HBM).
#define NCHUNK 32
#define CH_E (N_EDGES / NCHUNK)   // 50000 edges per chunk (25000 int2)
#define NW   16                   // waves per 1024-thread block
#define WSTG 552                  // per-wave staging cap: mean 390, sd 18.5, +8.7σ

// ---- workspace (4-byte words), ~9.1 MB ----
#define WS_BUCKET (R2 * CSTRIDE)
#define WS_OFFDEG (WS_BUCKET + R2 * CAP)
#define WS_G      (WS_OFFDEG + R2 * RN)

__global__ __launch_bounds__(1024) void bucket_own(
        const int* __restrict__ src, const int* __restrict__ dst,
        int* __restrict__ cursor, int* __restrict__ bucket) {
    __shared__ int stg[NW * WSTG];   // staged owned edges, per-wave regions
    __shared__ int wcnt[NW];
    __shared__ int cnt[R2];          // per-block count, owned ranges only
    __shared__ int cur[R2];
    int tid = threadIdx.x;
    int w = tid >> 6;
    unsigned own = blockIdx.x & 7;
    int chunk = blockIdx.x >> 3;
    if (tid < R2) cnt[tid] = 0;
    if (tid < NW) wcnt[tid] = 0;
    __syncthreads();

    const int2* d2 = (const int2*)(dst + (size_t)chunk * CH_E);
    const int2* s2 = (const int2*)(src + (size_t)chunk * CH_E);
    int* mystg = stg + w * WSTG;
    for (int i = tid; i < CH_E / 2; i += 1024) {
        int2 d = d2[i];
        int2 s = s2[i];
        {
            unsigned r = (unsigned)d.x / RN;
            if ((r & 7) == own) {
                unsigned dl = (unsigned)d.x - r * RN;
                int p = atomicAdd(&wcnt[w], 1);   // wave-local LDS counter
                if (p < WSTG) {
                    mystg[p] = (int)(((r >> 3) << 24) | (dl << 17) | (unsigned)s.x);
                    atomicAdd(&cnt[r], 1);
                }
            }
        }
        {
            unsigned r = (unsigned)d.y / RN;
            if ((r & 7) == own) {
                unsigned dl = (unsigned)d.y - r * RN;
                int p = atomicAdd(&wcnt[w], 1);
                if (p < WSTG) {
                    mystg[p] = (int)(((r >> 3) << 24) | (dl << 17) | (unsigned)s.y);
                    atomicAdd(&cnt[r], 1);
                }
            }
        }
    }
    __syncthreads();

    // Reserve: 128 owned ranges per block -> 32K global atomics total (8x fewer).
    for (int i = tid; i < R2; i += 1024) {
        if (((unsigned)i & 7) == own) {
            int c = cnt[i];
            cur[i] = (c > 0) ? atomicAdd(&cursor[i * CSTRIDE], c) : 0;
        }
    }
    __syncthreads();

    // Place from LDS staging: ~390 edges per wave; spans of ~49 contiguous
    // slots per (block,range) -> mostly full-line, single-writer stores.
    int mycnt = wcnt[w];
    if (mycnt > WSTG) mycnt = WSTG;
    for (int j = tid & 63; j < mycnt; j += 64) {
        int e = mystg[j];
        unsigned r = (((unsigned)e >> 24) << 3) | own;
        int slot = atomicAdd(&cur[r], 1);
        if (slot < CAP)
            bucket[(size_t)r * CAP + slot] = e & 0x00FFFFFF;
    }
}

// Layer 1 (proven sorted structure): LDS counting-sort of the range's edges
// to node order, 4-lane-per-node walk + distributed MLP. Dumps sorted CSR in
// place over the bucket region + offdeg, for the layer-2 gather walk.
__global__ __launch_bounds__(512) void sage1_range(
        const int* __restrict__ bucket, const int* __restrict__ cursor,
        const float* __restrict__ x,
        const float* __restrict__ W_l1, const float* __restrict__ b_l1,
        const float* __restrict__ W_r1,
        const float* __restrict__ W_l2, const float* __restrict__ b_l2,
        const float* __restrict__ W_r2,
        int* __restrict__ csr, int* __restrict__ offdeg,
        float* __restrict__ g, float* __restrict__ out_rt) {
    __shared__ int raw[CAP];
    __shared__ int seg[CAP];
    __shared__ int scnt[128];
    __shared__ int soff[128];
    __shared__ int scur[128];
    __shared__ int wtot[2];
    __shared__ float sWl[HID_CH * IN_CH];
    __shared__ float sWr[HID_CH * IN_CH];
    __shared__ float sb[HID_CH];
    __shared__ float sWl2[OUT_CH * HID_CH];
    __shared__ float sWr2[OUT_CH * HID_CH];
    __shared__ float sb2[OUT_CH];

    int tid = threadIdx.x;
    for (int i = tid; i < HID_CH * IN_CH; i += 512) {
        sWl[i] = W_l1[i];
        sWr[i] = W_r1[i];
    }
    for (int i = tid; i < HID_CH; i += 512) sb[i] = b_l1[i];
    for (int i = tid; i < OUT_CH * HID_CH; i += 512) {
        sWl2[i] = W_l2[i];
        sWr2[i] = W_r2[i];
    }
    if (tid < OUT_CH) sb2[tid] = b_l2[tid];
    if (tid < 128) scnt[tid] = 0;

    int r = blockIdx.x;
    int len = cursor[r * CSTRIDE];
    if (len > CAP) len = CAP;
    const int* bin = bucket + (size_t)r * CAP;
    for (int j = tid; j < len; j += 512) raw[j] = bin[j];
    __syncthreads();

    for (int j = tid; j < len; j += 512) atomicAdd(&scnt[raw[j] >> 17], 1);
    __syncthreads();

    // Exclusive scan over 128 slots (RN=98 padded): per-wave shfl scan, 2 waves.
    int lane = tid & 63;
    if (tid < 128) {
        int v = scnt[tid];
        int incl = v;
        #pragma unroll
        for (int d = 1; d < 64; d <<= 1) {
            int t2 = __shfl_up(incl, d);
            if (lane >= d) incl += t2;
        }
        if (lane == 63) wtot[tid >> 6] = incl;
        soff[tid] = incl - v;
    }
    __syncthreads();
    if (tid < 128) {
        int o = soff[tid] + ((tid >= 64) ? wtot[0] : 0);
        soff[tid] = o;
        scur[tid] = o;
    }
    __syncthreads();

    for (int j = tid; j < len; j += 512) {
        int w = raw[j];
        int p = atomicAdd(&scur[w >> 17], 1);
        seg[p] = w & 0x1FFFF;
    }
    __syncthreads();

    // Dump node-sorted CSR in place over the bucket region (coalesced).
    int* cw = csr + (size_t)r * CAP;
    for (int j = tid; j < len; j += 512) cw[j] = seg[j];

    // Walk: 4 lanes per node, independent (pipelineable) LDS + global loads.
    int q = tid >> 2;
    int l = tid & 3;
    int node = r * RN + q;
    if (q < RN && node < N_NODES) {
        int o = soff[q];
        int dn = scnt[q];
        if (l == 0) offdeg[node] = o | (dn << 16);

        float acc[IN_CH];
        #pragma unroll
        for (int c = 0; c < IN_CH; c++) acc[c] = 0.0f;
        for (int j = o + l; j < o + dn; j += 4) {
            int s = seg[j];
            const float4* xs = (const float4*)(x + (size_t)s * IN_CH);
            float4 a = xs[0];
            float4 b = xs[1];
            acc[0] += a.x; acc[1] += a.y; acc[2] += a.z; acc[3] += a.w;
            acc[4] += b.x; acc[5] += b.y; acc[6] += b.z; acc[7] += b.w;
        }
        #pragma unroll
        for (int c = 0; c < IN_CH; c++) {
            acc[c] += __shfl_xor(acc[c], 1);
            acc[c] += __shfl_xor(acc[c], 2);
        }
        float inv = 1.0f / fmaxf((float)dn, 1.0f);
        float ag[IN_CH], xa[IN_CH];
        #pragma unroll
        for (int c = 0; c < IN_CH; c++) ag[c] = acc[c] * inv;
        const float4* xp = (const float4*)(x + (size_t)node * IN_CH);
        float4 x0 = xp[0], x1 = xp[1];
        xa[0] = x0.x; xa[1] = x0.y; xa[2] = x0.z; xa[3] = x0.w;
        xa[4] = x1.x; xa[5] = x1.y; xa[6] = x1.z; xa[7] = x1.w;

        // Distributed MLP: lane l handles hidden units [16l, 16l+16).
        float g0 = 0.f, g1 = 0.f, r0 = 0.f, r1 = 0.f;
        int k0 = l * 16;
        #pragma unroll 4
        for (int kk = k0; kk < k0 + 16; kk++) {
            float hk = sb[kk];
            #pragma unroll
            for (int c = 0; c < IN_CH; c++) {
                hk += sWl[kk * IN_CH + c] * ag[c];
                hk += sWr[kk * IN_CH + c] * xa[c];
            }
            hk = fmaxf(hk, 0.0f);   // ReLU (dropout identity in eval)
            g0 += sWl2[kk] * hk;
            g1 += sWl2[HID_CH + kk] * hk;
            r0 += sWr2[kk] * hk;
            r1 += sWr2[HID_CH + kk] * hk;
        }
        g0 += __shfl_xor(g0, 1); g0 += __shfl_xor(g0, 2);
        g1 += __shfl_xor(g1, 1); g1 += __shfl_xor(g1, 2);
        r0 += __shfl_xor(r0, 1); r0 += __shfl_xor(r0, 2);
        r1 += __shfl_xor(r1, 1); r1 += __shfl_xor(r1, 2);
        if (l == 0) {
            g[(size_t)node * 2 + 0] = g0;
            g[(size_t)node * 2 + 1] = g1;
            float2 rt;
            rt.x = r0 + sb2[0];
            rt.y = r1 + sb2[1];
            *(float2*)(out_rt + (size_t)node * 2) = rt;
        }
    }
}

// Layer 2 (round-0 walk, measured ~18us): 4 lanes/node read the node's
// contiguous CSR span from global (L1/L2-hot window per range), gather g[src],
// shfl-reduce; out = sum/max(dn,1) + rt. No LDS, no barriers, no atomics.
__global__ __launch_bounds__(256) void sage2_kernel(
        const int* __restrict__ csr, const int* __restrict__ offdeg,
        const float* __restrict__ g, float* __restrict__ out) {
    int t = blockIdx.x * blockDim.x + threadIdx.x;
    int node = t >> 2;
    int l = t & 3;
    if (node >= N_NODES) return;
    int r = node / RN;
    int od = offdeg[node];
    int o = od & 0xFFFF;
    int dn = od >> 16;
    const int* seg = csr + (size_t)r * CAP;
    float a0 = 0.f, a1 = 0.f;
    for (int j = o + l; j < o + dn; j += 4) {
        int s = seg[j];
        float2 gv = *(const float2*)(g + (size_t)s * 2);
        a0 += gv.x;
        a1 += gv.y;
    }
    a0 += __shfl_xor(a0, 1); a0 += __shfl_xor(a0, 2);
    a1 += __shfl_xor(a1, 1); a1 += __shfl_xor(a1, 2);
    if (l == 0) {
        float inv = 1.0f / fmaxf((float)dn, 1.0f);
        float2 rt = *(const float2*)(out + (size_t)node * 2);
        float2 ov;
        ov.x = a0 * inv + rt.x;
        ov.y = a1 * inv + rt.y;
        *(float2*)(out + (size_t)node * 2) = ov;
    }
}

extern "C" void kernel_launch(void* const* d_in, const int* in_sizes, int n_in,
                              void* d_out, int out_size, void* d_ws, size_t ws_size,
                              hipStream_t stream) {
    const float* x    = (const float*)d_in[0];
    const int*   ei   = (const int*)d_in[1];   // [2, N_EDGES] int32 per harness
    const float* W_l1 = (const float*)d_in[2];
    const float* b_l1 = (const float*)d_in[3];
    const float* W_r1 = (const float*)d_in[4];
    const float* W_l2 = (const float*)d_in[5];
    const float* b_l2 = (const float*)d_in[6];
    const float* W_r2 = (const float*)d_in[7];
    float* out = (float*)d_out;

    const int* src = ei;
    const int* dst = ei + N_EDGES;

    int*   cursor = (int*)d_ws;
    int*   bucket = (int*)d_ws + WS_BUCKET;
    int*   offdeg = (int*)d_ws + WS_OFFDEG;
    float* g      = (float*)d_ws + WS_G;

    hipMemsetAsync(cursor, 0, R2 * CSTRIDE * sizeof(int), stream);

    bucket_own<<<NCHUNK * 8, 1024, 0, stream>>>(src, dst, cursor, bucket);
    sage1_range<<<R2, 512, 0, stream>>>(bucket, cursor, x,
                                        W_l1, b_l1, W_r1, W_l2, b_l2, W_r2,
                                        bucket /*csr in place*/, offdeg, g, out);
    sage2_kernel<<<(4 * N_NODES + 255) / 256, 256, 0, stream>>>(bucket, offdeg, g, out);
}

// Round 8
// 134.328 us; speedup vs baseline: 7.1718x; 1.0112x over previous
//
#include <hip/hip_runtime.h>

#define N_NODES 100000
#define N_EDGES 1600000
#define IN_CH 8
#define HID_CH 64
#define OUT_CH 2

// 1024 dst-ranges of 98 nodes (1024*98 = 100352 >= 100000).
#define R2   1024
#define RN   98
#define CAP  1920    // per-range capacity; Binom mean 1568, sd ~40 -> +8.9 sigma
#define CSTRIDE 16   // cursor padded to one range per 64B line

// Ownership-filtered binning: 256 blocks = 32 chunks x 8 owners.
// ROUND-8 REMAP: chunk = blockIdx&31, own = blockIdx>>5. The 8 owner blocks
// of chunk c are {c, c+32, ..., c+224}, all == c (mod 8) -> SAME XCD under
// the round-robin block->XCD dispatch, so the chunk is HBM-fetched once and
// the other 7 scans hit that XCD's L2 (was: consecutive blockIdx = 8
// different XCDs = 8x redundant HBM fetch, ~90MB extra).
#define NCHUNK 32
#define CH_E (N_EDGES / NCHUNK)   // 50000 edges per chunk (25000 int2)
#define NW   16                   // waves per 1024-thread block
#define WSTG 552                  // per-wave staging cap: mean 390, sd 18.5, +8.7σ

// ---- workspace (4-byte words), ~9.1 MB ----
#define WS_BUCKET (R2 * CSTRIDE)
#define WS_OFFDEG (WS_BUCKET + R2 * CAP)
#define WS_G      (WS_OFFDEG + R2 * RN)

__global__ __launch_bounds__(1024) void bucket_own(
        const int* __restrict__ src, const int* __restrict__ dst,
        int* __restrict__ cursor, int* __restrict__ bucket) {
    __shared__ int stg[NW * WSTG];   // staged owned edges, per-wave regions
    __shared__ int wcnt[NW];
    __shared__ int cnt[R2];          // per-block count, owned ranges only
    __shared__ int cur[R2];
    int tid = threadIdx.x;
    int w = tid >> 6;
    unsigned own = blockIdx.x >> 5;  // XCD-colocated ownership (see above)
    int chunk = blockIdx.x & 31;
    if (tid < R2) cnt[tid] = 0;
    if (tid < NW) wcnt[tid] = 0;
    __syncthreads();

    const int2* d2 = (const int2*)(dst + (size_t)chunk * CH_E);
    const int2* s2 = (const int2*)(src + (size_t)chunk * CH_E);
    int* mystg = stg + w * WSTG;
    for (int i = tid; i < CH_E / 2; i += 1024) {
        int2 d = d2[i];
        int2 s = s2[i];
        {
            unsigned r = (unsigned)d.x / RN;
            if ((r & 7) == own) {
                unsigned dl = (unsigned)d.x - r * RN;
                int p = atomicAdd(&wcnt[w], 1);   // wave-local LDS counter
                if (p < WSTG) {
                    mystg[p] = (int)(((r >> 3) << 24) | (dl << 17) | (unsigned)s.x);
                    atomicAdd(&cnt[r], 1);
                }
            }
        }
        {
            unsigned r = (unsigned)d.y / RN;
            if ((r & 7) == own) {
                unsigned dl = (unsigned)d.y - r * RN;
                int p = atomicAdd(&wcnt[w], 1);
                if (p < WSTG) {
                    mystg[p] = (int)(((r >> 3) << 24) | (dl << 17) | (unsigned)s.y);
                    atomicAdd(&cnt[r], 1);
                }
            }
        }
    }
    __syncthreads();

    // Reserve: 128 owned ranges per block -> 32K global atomics total.
    for (int i = tid; i < R2; i += 1024) {
        if (((unsigned)i & 7) == own) {
            int c = cnt[i];
            cur[i] = (c > 0) ? atomicAdd(&cursor[i * CSTRIDE], c) : 0;
        }
    }
    __syncthreads();

    // Place from LDS staging: ~390 edges per wave; spans of ~49 contiguous
    // slots per (block,range) -> mostly full-line, single-writer stores.
    int mycnt = wcnt[w];
    if (mycnt > WSTG) mycnt = WSTG;
    for (int j = tid & 63; j < mycnt; j += 64) {
        int e = mystg[j];
        unsigned r = (((unsigned)e >> 24) << 3) | own;
        int slot = atomicAdd(&cur[r], 1);
        if (slot < CAP)
            bucket[(size_t)r * CAP + slot] = e & 0x00FFFFFF;
    }
}

// Layer 1 (proven sorted structure): LDS counting-sort of the range's edges
// to node order, 4-lane-per-node walk + distributed MLP. Dumps sorted CSR in
// place over the bucket region + offdeg, for the layer-2 gather walk.
__global__ __launch_bounds__(512) void sage1_range(
        const int* __restrict__ bucket, const int* __restrict__ cursor,
        const float* __restrict__ x,
        const float* __restrict__ W_l1, const float* __restrict__ b_l1,
        const float* __restrict__ W_r1,
        const float* __restrict__ W_l2, const float* __restrict__ b_l2,
        const float* __restrict__ W_r2,
        int* __restrict__ csr, int* __restrict__ offdeg,
        float* __restrict__ g, float* __restrict__ out_rt) {
    __shared__ int raw[CAP];
    __shared__ int seg[CAP];
    __shared__ int scnt[128];
    __shared__ int soff[128];
    __shared__ int scur[128];
    __shared__ int wtot[2];
    __shared__ float sWl[HID_CH * IN_CH];
    __shared__ float sWr[HID_CH * IN_CH];
    __shared__ float sb[HID_CH];
    __shared__ float sWl2[OUT_CH * HID_CH];
    __shared__ float sWr2[OUT_CH * HID_CH];
    __shared__ float sb2[OUT_CH];

    int tid = threadIdx.x;
    for (int i = tid; i < HID_CH * IN_CH; i += 512) {
        sWl[i] = W_l1[i];
        sWr[i] = W_r1[i];
    }
    for (int i = tid; i < HID_CH; i += 512) sb[i] = b_l1[i];
    for (int i = tid; i < OUT_CH * HID_CH; i += 512) {
        sWl2[i] = W_l2[i];
        sWr2[i] = W_r2[i];
    }
    if (tid < OUT_CH) sb2[tid] = b_l2[tid];
    if (tid < 128) scnt[tid] = 0;

    int r = blockIdx.x;
    int len = cursor[r * CSTRIDE];
    if (len > CAP) len = CAP;
    const int* bin = bucket + (size_t)r * CAP;
    for (int j = tid; j < len; j += 512) raw[j] = bin[j];
    __syncthreads();

    for (int j = tid; j < len; j += 512) atomicAdd(&scnt[raw[j] >> 17], 1);
    __syncthreads();

    // Exclusive scan over 128 slots (RN=98 padded): per-wave shfl scan, 2 waves.
    int lane = tid & 63;
    if (tid < 128) {
        int v = scnt[tid];
        int incl = v;
        #pragma unroll
        for (int d = 1; d < 64; d <<= 1) {
            int t2 = __shfl_up(incl, d);
            if (lane >= d) incl += t2;
        }
        if (lane == 63) wtot[tid >> 6] = incl;
        soff[tid] = incl - v;
    }
    __syncthreads();
    if (tid < 128) {
        int o = soff[tid] + ((tid >= 64) ? wtot[0] : 0);
        soff[tid] = o;
        scur[tid] = o;
    }
    __syncthreads();

    for (int j = tid; j < len; j += 512) {
        int w = raw[j];
        int p = atomicAdd(&scur[w >> 17], 1);
        seg[p] = w & 0x1FFFF;
    }
    __syncthreads();

    // Dump node-sorted CSR in place over the bucket region (coalesced).
    int* cw = csr + (size_t)r * CAP;
    for (int j = tid; j < len; j += 512) cw[j] = seg[j];

    // Walk: 4 lanes per node, independent (pipelineable) LDS + global loads.
    int q = tid >> 2;
    int l = tid & 3;
    int node = r * RN + q;
    if (q < RN && node < N_NODES) {
        int o = soff[q];
        int dn = scnt[q];
        if (l == 0) offdeg[node] = o | (dn << 16);

        float acc[IN_CH];
        #pragma unroll
        for (int c = 0; c < IN_CH; c++) acc[c] = 0.0f;
        for (int j = o + l; j < o + dn; j += 4) {
            int s = seg[j];
            const float4* xs = (const float4*)(x + (size_t)s * IN_CH);
            float4 a = xs[0];
            float4 b = xs[1];
            acc[0] += a.x; acc[1] += a.y; acc[2] += a.z; acc[3] += a.w;
            acc[4] += b.x; acc[5] += b.y; acc[6] += b.z; acc[7] += b.w;
        }
        #pragma unroll
        for (int c = 0; c < IN_CH; c++) {
            acc[c] += __shfl_xor(acc[c], 1);
            acc[c] += __shfl_xor(acc[c], 2);
        }
        float inv = 1.0f / fmaxf((float)dn, 1.0f);
        float ag[IN_CH], xa[IN_CH];
        #pragma unroll
        for (int c = 0; c < IN_CH; c++) ag[c] = acc[c] * inv;
        const float4* xp = (const float4*)(x + (size_t)node * IN_CH);
        float4 x0 = xp[0], x1 = xp[1];
        xa[0] = x0.x; xa[1] = x0.y; xa[2] = x0.z; xa[3] = x0.w;
        xa[4] = x1.x; xa[5] = x1.y; xa[6] = x1.z; xa[7] = x1.w;

        // Distributed MLP: lane l handles hidden units [16l, 16l+16).
        float g0 = 0.f, g1 = 0.f, r0 = 0.f, r1 = 0.f;
        int k0 = l * 16;
        #pragma unroll 4
        for (int kk = k0; kk < k0 + 16; kk++) {
            float hk = sb[kk];
            #pragma unroll
            for (int c = 0; c < IN_CH; c++) {
                hk += sWl[kk * IN_CH + c] * ag[c];
                hk += sWr[kk * IN_CH + c] * xa[c];
            }
            hk = fmaxf(hk, 0.0f);   // ReLU (dropout identity in eval)
            g0 += sWl2[kk] * hk;
            g1 += sWl2[HID_CH + kk] * hk;
            r0 += sWr2[kk] * hk;
            r1 += sWr2[HID_CH + kk] * hk;
        }
        g0 += __shfl_xor(g0, 1); g0 += __shfl_xor(g0, 2);
        g1 += __shfl_xor(g1, 1); g1 += __shfl_xor(g1, 2);
        r0 += __shfl_xor(r0, 1); r0 += __shfl_xor(r0, 2);
        r1 += __shfl_xor(r1, 1); r1 += __shfl_xor(r1, 2);
        if (l == 0) {
            g[(size_t)node * 2 + 0] = g0;
            g[(size_t)node * 2 + 1] = g1;
            float2 rt;
            rt.x = r0 + sb2[0];
            rt.y = r1 + sb2[1];
            *(float2*)(out_rt + (size_t)node * 2) = rt;
        }
    }
}

// Layer 2 (round-0 walk): 4 lanes/node read the node's contiguous CSR span
// from global (L1/L2-hot window per range), gather g[src], shfl-reduce;
// out = sum/max(dn,1) + rt. No LDS, no barriers, no atomics.
__global__ __launch_bounds__(256) void sage2_kernel(
        const int* __restrict__ csr, const int* __restrict__ offdeg,
        const float* __restrict__ g, float* __restrict__ out) {
    int t = blockIdx.x * blockDim.x + threadIdx.x;
    int node = t >> 2;
    int l = t & 3;
    if (node >= N_NODES) return;
    int r = node / RN;
    int od = offdeg[node];
    int o = od & 0xFFFF;
    int dn = od >> 16;
    const int* seg = csr + (size_t)r * CAP;
    float a0 = 0.f, a1 = 0.f;
    for (int j = o + l; j < o + dn; j += 4) {
        int s = seg[j];
        float2 gv = *(const float2*)(g + (size_t)s * 2);
        a0 += gv.x;
        a1 += gv.y;
    }
    a0 += __shfl_xor(a0, 1); a0 += __shfl_xor(a0, 2);
    a1 += __shfl_xor(a1, 1); a1 += __shfl_xor(a1, 2);
    if (l == 0) {
        float inv = 1.0f / fmaxf((float)dn, 1.0f);
        float2 rt = *(const float2*)(out + (size_t)node * 2);
        float2 ov;
        ov.x = a0 * inv + rt.x;
        ov.y = a1 * inv + rt.y;
        *(float2*)(out + (size_t)node * 2) = ov;
    }
}

extern "C" void kernel_launch(void* const* d_in, const int* in_sizes, int n_in,
                              void* d_out, int out_size, void* d_ws, size_t ws_size,
                              hipStream_t stream) {
    const float* x    = (const float*)d_in[0];
    const int*   ei   = (const int*)d_in[1];   // [2, N_EDGES] int32 per harness
    const float* W_l1 = (const float*)d_in[2];
    const float* b_l1 = (const float*)d_in[3];
    const float* W_r1 = (const float*)d_in[4];
    const float* W_l2 = (const float*)d_in[5];
    const float* b_l2 = (const float*)d_in[6];
    const float* W_r2 = (const float*)d_in[7];
    float* out = (float*)d_out;

    const int* src = ei;
    const int* dst = ei + N_EDGES;

    int*   cursor = (int*)d_ws;
    int*   bucket = (int*)d_ws + WS_BUCKET;
    int*   offdeg = (int*)d_ws + WS_OFFDEG;
    float* g      = (float*)d_ws + WS_G;

    hipMemsetAsync(cursor, 0, R2 * CSTRIDE * sizeof(int), stream);

    bucket_own<<<NCHUNK * 8, 1024, 0, stream>>>(src, dst, cursor, bucket);
    sage1_range<<<R2, 512, 0, stream>>>(bucket, cursor, x,
                                        W_l1, b_l1, W_r1, W_l2, b_l2, W_r2,
                                        bucket /*csr in place*/, offdeg, g, out);
    sage2_kernel<<<(4 * N_NODES + 255) / 256, 256, 0, stream>>>(bucket, offdeg, g, out);
}